// Round 5
// baseline (143.178 us; speedup 1.0000x reference)
//
#include <hip/hip_runtime.h>
#include <hip/hip_bf16.h>

#define L 4096
#define NT 256
#define PPT 16          // elements per thread
#define NPASS 3         // 4-bit digits over 12-bit truncated label key (bits 20..31)

// Padded LDS index: +1 word per 16 -> conflict-free chunk access
__device__ __forceinline__ int PIDX(int p) { return p + (p >> 4); }
#define PADSZ (L + L / 16)   // 4352

__global__ void zero_out_kernel(float* out) { out[0] = 0.0f; }

// x += dpp_move(x); masked/out-of-bounds lanes add 0.
template <int CTRL, int RM>
__device__ __forceinline__ unsigned dpp_add(unsigned x) {
  return x + (unsigned)__builtin_amdgcn_update_dpp(0, (int)x, CTRL, RM, 0xF, false);
}

// Wave64 inclusive +scan of 8 independent u32 (each = 2 packed u16 counters).
__device__ __forceinline__ void wave_incl_scan8(unsigned v[8]) {
#pragma unroll
  for (int k = 0; k < 8; ++k) {
    unsigned x = v[k];
    x = dpp_add<0x111, 0xF>(x);   // row_shr:1
    x = dpp_add<0x112, 0xF>(x);   // row_shr:2
    x = dpp_add<0x114, 0xF>(x);   // row_shr:4
    x = dpp_add<0x118, 0xF>(x);   // row_shr:8
    x = dpp_add<0x142, 0xA>(x);   // row_bcast:15 -> rows 1,3
    x = dpp_add<0x143, 0xC>(x);   // row_bcast:31 -> rows 2,3
    v[k] = x;
  }
}

// Extract u16 entry d (0..15) from 8 packed u32s via cndmask tree.
__device__ __forceinline__ unsigned sel16(const unsigned c[8], int d) {
  unsigned a0 = (d & 2) ? c[1] : c[0];
  unsigned a1 = (d & 2) ? c[3] : c[2];
  unsigned a2 = (d & 2) ? c[5] : c[4];
  unsigned a3 = (d & 2) ? c[7] : c[6];
  unsigned b0 = (d & 4) ? a1 : a0;
  unsigned b1 = (d & 4) ? a3 : a2;
  unsigned w  = (d & 8) ? b1 : b0;
  return (w >> ((d & 1) * 16)) & 0xFFFFu;
}

__global__ __launch_bounds__(NT) void listmle_kernel(
    const float* __restrict__ preds, const float* __restrict__ labels,
    float* __restrict__ out, float invB) {
  __shared__ unsigned int bufA[PADSZ];      // 17 KB
  __shared__ unsigned int bufB[PADSZ];      // 17 KB
  __shared__ uint4 wt4[8];                  // per-wave packed digit totals
  __shared__ float wredf[4];
  __shared__ float wmax[4];
  __shared__ float sM, sSum;

  const int tid = threadIdx.x;
  const int lane = tid & 63;
  const int wave = tid >> 6;
  const float* __restrict__ prow = preds + (size_t)blockIdx.x * L;
  const float* __restrict__ lrow = labels + (size_t)blockIdx.x * L;

  // ---- chunk-order vector loads; 12-bit keys straight to LDS ----
  float lmax = -INFINITY, lsum = 0.0f;
  {
    const float4* p4 = reinterpret_cast<const float4*>(prow) + tid * 4;
    const float4* l4 = reinterpret_cast<const float4*>(lrow) + tid * 4;
#pragma unroll
    for (int q = 0; q < 4; ++q) {
      float4 p = p4[q];
      float4 lb = l4[q];
      float pe[4] = {p.x, p.y, p.z, p.w};
      float le[4] = {lb.x, lb.y, lb.z, lb.w};
#pragma unroll
      for (int r = 0; r < 4; ++r) {
        lmax = fmaxf(lmax, pe[r]);
        lsum += pe[r];
        unsigned u = __float_as_uint(le[r]);
        unsigned s = (u & 0x80000000u) ? ~u : (u | 0x80000000u);  // ascending sortable
        int i = tid * PPT + q * 4 + r;
        bufA[PIDX(i)] = (~s & 0xFFF00000u) | (unsigned)i;         // key12 | idx
      }
    }
  }
  for (int off = 32; off; off >>= 1) {
    lmax = fmaxf(lmax, __shfl_down(lmax, off));
    lsum += __shfl_down(lsum, off);
  }
  if (lane == 0) { wmax[wave] = lmax; wredf[wave] = lsum; }
  __syncthreads();                          // keys + wave reductions published
  if (tid == 0) {
    float m = wmax[0], s2 = wredf[0];
    for (int w = 1; w < 4; ++w) { m = fmaxf(m, wmax[w]); s2 += wredf[w]; }
    sM = m; sSum = s2;                      // consumed >=2 barriers later
  }

  // ---- LSD radix: 3 passes of 4 bits; kv re-read from LDS (no reg arrays) ----
  unsigned int* src = bufA;
  unsigned int* dst = bufB;
#pragma unroll
  for (int pass = 0; pass < NPASS; ++pass) {
    const int sh = 20 + 4 * pass;
    // count + stable local ranks (16 x 8-bit counters in c0,c1; ranks in clpack)
    unsigned long long c0 = 0, c1 = 0, clpack = 0;
#pragma unroll
    for (int e = 0; e < PPT; ++e) {
      unsigned v = src[PIDX(tid * PPT + e)];
      int d = (v >> sh) & 15;
      int s8 = (d & 7) * 8;
      unsigned long long cur = (d < 8) ? c0 : c1;
      unsigned cl = (unsigned)((cur >> s8) & 0xFFu);
      cur += (1ull << s8);
      if (d < 8) c0 = cur; else c1 = cur;
      clpack |= (unsigned long long)cl << (4 * e);
    }
    // expand to 16 x u16 packed in 8 u32; DPP wave scan (pure VALU)
    unsigned own[8], incl[8];
#pragma unroll
    for (int k = 0; k < 4; ++k) {
      own[k]     = (unsigned)((c0 >> (16 * k)) & 0xFFu) |
                   ((unsigned)((c0 >> (16 * k + 8)) & 0xFFu) << 16);
      own[4 + k] = (unsigned)((c1 >> (16 * k)) & 0xFFu) |
                   ((unsigned)((c1 >> (16 * k + 8)) & 0xFFu) << 16);
    }
#pragma unroll
    for (int k = 0; k < 8; ++k) incl[k] = own[k];
    wave_incl_scan8(incl);
    if (lane == 63) {
      wt4[wave * 2]     = make_uint4(incl[0], incl[1], incl[2], incl[3]);
      wt4[wave * 2 + 1] = make_uint4(incl[4], incl[5], incl[6], incl[7]);
    }
    __syncthreads();                       // barrier 1: wave totals published
    // block digit totals + my wave's exclusive prefix (packed u16, sums <= 4096)
    unsigned comb[8];
    {
      unsigned cum[8] = {0,0,0,0,0,0,0,0}, tot[8] = {0,0,0,0,0,0,0,0};
#pragma unroll
      for (int w = 0; w < 4; ++w) {
        uint4 a = wt4[w * 2], b = wt4[w * 2 + 1];
        unsigned tw[8] = {a.x, a.y, a.z, a.w, b.x, b.y, b.z, b.w};
#pragma unroll
        for (int k = 0; k < 8; ++k) {
          tot[k] += tw[k];
          if (w < wave) cum[k] += tw[k];   // wave-uniform predicate
        }
      }
      unsigned run = 0;
#pragma unroll
      for (int k = 0; k < 8; ++k) {
        unsigned t0 = tot[k] & 0xFFFFu, t1 = tot[k] >> 16;
        unsigned b0 = run; run += t0;
        unsigned b1 = run; run += t1;
        comb[k] = (b0 | (b1 << 16)) + cum[k] + (incl[k] - own[k]);
      }
    }
    // stable scatter; kv re-read from src (still intact)
    if (pass == NPASS - 1) {
      const float M = sM;
#pragma unroll
      for (int e = 0; e < PPT; ++e) {
        unsigned v = src[PIDX(tid * PPT + e)];
        int d = (v >> sh) & 15;
        unsigned base = sel16(comb, d);
        unsigned cl = (unsigned)((clpack >> (4 * e)) & 15);
        int idx = (int)(v & 0xFFFu);
        float evv = __expf(prow[idx] - M);     // cached-row gather
        dst[PIDX((int)(base + cl))] = __float_as_uint(evv);
      }
    } else {
#pragma unroll
      for (int e = 0; e < PPT; ++e) {
        unsigned v = src[PIDX(tid * PPT + e)];
        int d = (v >> sh) & 15;
        unsigned base = sel16(comb, d);
        unsigned cl = (unsigned)((clpack >> (4 * e)) & 15);
        dst[PIDX((int)(base + cl))] = v;
      }
    }
    __syncthreads();                       // barrier 2: scatter done
    unsigned int* t = src; src = dst; dst = t;
  }
  // sorted exp-values in bufB (A->B, B->A, A->B)

  // ---- suffix (reverse inclusive) scan of exp values ----
  float run = 0.0f;
#pragma unroll
  for (int e = 0; e < PPT; ++e)
    run += __uint_as_float(bufB[PIDX(tid * PPT + e)]);
  float s = run;                       // wave suffix-inclusive scan of chunk totals
  for (int off = 1; off < 64; off <<= 1) {
    float v = __shfl_down(s, off);
    if (lane + off < 64) s += v;
  }
  if (lane == 0) wredf[wave] = s;      // wave totals
  __syncthreads();
  float O = s - run;                   // later chunks within wave
  for (int w = wave + 1; w < 4; ++w) O += wredf[w];

  float acc = 0.0f, slog = 0.0f;
#pragma unroll
  for (int e = PPT - 1; e >= 0; --e) {
    acc += __uint_as_float(bufB[PIDX(tid * PPT + e)]);
    slog += __logf(acc + O);
  }

  for (int off = 32; off; off >>= 1) slog += __shfl_down(slog, off);
  if (lane == 0) wmax[wave] = slog;    // reuse as scratch
  __syncthreads();
  if (tid == 0) {
    float tot2 = wmax[0] + wmax[1] + wmax[2] + wmax[3];
    float rowval = (float)L * sM + tot2 - sSum;
    atomicAdd(out, rowval * invB);
  }
}

extern "C" void kernel_launch(void* const* d_in, const int* in_sizes, int n_in,
                              void* d_out, int out_size, void* d_ws, size_t ws_size,
                              hipStream_t stream) {
  const float* preds = (const float*)d_in[0];
  const float* labels = (const float*)d_in[1];
  float* out = (float*)d_out;
  const int B = in_sizes[0] / L;

  zero_out_kernel<<<1, 1, 0, stream>>>(out);
  listmle_kernel<<<B, NT, 0, stream>>>(preds, labels, out, 1.0f / (float)B);
}

// Round 6
// 114.385 us; speedup vs baseline: 1.2517x; 1.2517x over previous
//
#include <hip/hip_runtime.h>

#define L 4096
#define NT 256
#define PPT 16
__device__ __forceinline__ int PIDX(int p) { return p + (p >> 4); }
#define PADSZ (L + L / 16)   // 4352

__global__ void zero_out_kernel(float* out) { out[0] = 0.0f; }

// x += dpp_move(x); masked/out-of-bounds lanes add 0.
template <int CTRL, int RM>
__device__ __forceinline__ unsigned dpp_add(unsigned x) {
  return x + (unsigned)__builtin_amdgcn_update_dpp(0, (int)x, CTRL, RM, 0xF, false);
}
// Wave64 inclusive +scan (pure VALU, no LDS).
__device__ __forceinline__ unsigned wave_incl_scan(unsigned x) {
  x = dpp_add<0x111, 0xF>(x);   // row_shr:1
  x = dpp_add<0x112, 0xF>(x);   // row_shr:2
  x = dpp_add<0x114, 0xF>(x);   // row_shr:4
  x = dpp_add<0x118, 0xF>(x);   // row_shr:8
  x = dpp_add<0x142, 0xA>(x);   // row_bcast:15 -> rows 1,3
  x = dpp_add<0x143, 0xC>(x);   // row_bcast:31 -> rows 2,3
  return x;
}

__device__ __forceinline__ unsigned label_key12(float lb) {
  unsigned u = __float_as_uint(lb);
  unsigned s = (u & 0x80000000u) ? ~u : (u | 0x80000000u);  // ascending sortable
  return (~s) >> 20;                                        // 12-bit descending key
}

__global__ __launch_bounds__(NT) __attribute__((amdgpu_waves_per_eu(2, 4)))
void listmle_kernel(const float* __restrict__ preds,
                    const float* __restrict__ labels,
                    float* __restrict__ out, float invB) {
  __shared__ unsigned hist[PADSZ];   // 17 KB: counts -> exclusive bases -> next-pos
  __shared__ unsigned buf[PADSZ];    // 17 KB: scattered exp(pred - M)
  __shared__ float wredf[4], wmax[4];
  __shared__ unsigned wscan[4];

  const int tid = threadIdx.x;
  const int lane = tid & 63;
  const int wave = tid >> 6;
  const float* __restrict__ prow = preds + (size_t)blockIdx.x * L;
  const float* __restrict__ lrow = labels + (size_t)blockIdx.x * L;

  // ---- zero hist (coalesced, conflict-free) ----
  for (int k = tid; k < PADSZ; k += NT) hist[k] = 0u;

  // issue global loads before the barrier (latency overlaps barrier wait)
  const float4* p4 = reinterpret_cast<const float4*>(prow) + tid * 4;
  const float4* l4 = reinterpret_cast<const float4*>(lrow) + tid * 4;
  float4 pv0 = p4[0], pv1 = p4[1], pv2 = p4[2], pv3 = p4[3];
  float4 lv0 = l4[0], lv1 = l4[1], lv2 = l4[2], lv3 = l4[3];
  float pe[PPT] = {pv0.x, pv0.y, pv0.z, pv0.w, pv1.x, pv1.y, pv1.z, pv1.w,
                   pv2.x, pv2.y, pv2.z, pv2.w, pv3.x, pv3.y, pv3.z, pv3.w};
  float le[PPT] = {lv0.x, lv0.y, lv0.z, lv0.w, lv1.x, lv1.y, lv1.z, lv1.w,
                   lv2.x, lv2.y, lv2.z, lv2.w, lv3.x, lv3.y, lv3.z, lv3.w};
  __syncthreads();                     // barrier 1: hist zeroed

  // ---- phase 1: histogram + max/sum reductions ----
  float lmax = -INFINITY, lsum = 0.0f;
#pragma unroll
  for (int e = 0; e < PPT; ++e) {
    lmax = fmaxf(lmax, pe[e]);
    lsum += pe[e];
    atomicAdd(&hist[PIDX((int)label_key12(le[e]))], 1u);
  }
  for (int off = 32; off; off >>= 1) {
    lmax = fmaxf(lmax, __shfl_down(lmax, off));
    lsum += __shfl_down(lsum, off);
  }
  if (lane == 0) { wmax[wave] = lmax; wredf[wave] = lsum; }
  __syncthreads();                     // barrier 2: hist + wave partials done
  const float M = fmaxf(fmaxf(wmax[0], wmax[1]), fmaxf(wmax[2], wmax[3]));
  const float S = wredf[0] + wredf[1] + wredf[2] + wredf[3];

  // ---- phase 2: exclusive scan of 4096 counters ----
  unsigned h[PPT], tot = 0;
#pragma unroll
  for (int e = 0; e < PPT; ++e) {
    unsigned v = hist[PIDX(tid * PPT + e)];
    h[e] = tot;
    tot += v;
  }
  unsigned incl = wave_incl_scan(tot);
  if (lane == 63) wscan[wave] = incl;
  __syncthreads();                     // barrier 3: wave scan totals
  unsigned base = incl - tot;
#pragma unroll
  for (int w = 0; w < 4; ++w)
    if (w < wave) base += wscan[w];    // wave-uniform predicate
#pragma unroll
  for (int e = 0; e < PPT; ++e)
    hist[PIDX(tid * PPT + e)] = base + h[e];   // becomes next-pos counter
  __syncthreads();                     // barrier 4: bases published

  // ---- phase 3: rank via atomic, scatter exp(pred - M) ----
#pragma unroll
  for (int e = 0; e < PPT; ++e) {
    unsigned key = label_key12(le[e]);
    unsigned pos = atomicAdd(&hist[PIDX((int)key)], 1u);
    buf[PIDX((int)pos)] = __float_as_uint(__expf(pe[e] - M));
  }
  __syncthreads();                     // barrier 5: scatter complete

  // ---- phase 4: suffix (reverse inclusive) scan + sum of logs ----
  float run = 0.0f;
#pragma unroll
  for (int e = 0; e < PPT; ++e)
    run += __uint_as_float(buf[PIDX(tid * PPT + e)]);
  float s = run;                       // wave suffix-inclusive scan of chunk totals
  for (int off = 1; off < 64; off <<= 1) {
    float v = __shfl_down(s, off);
    if (lane + off < 64) s += v;
  }
  if (lane == 0) wredf[wave] = s;      // wave totals (safe: old reads done pre-b2..b4)
  __syncthreads();                     // barrier 6
  float O = s - run;                   // later chunks within wave
  for (int w = wave + 1; w < 4; ++w) O += wredf[w];

  float acc = 0.0f, slog = 0.0f;
#pragma unroll
  for (int e = PPT - 1; e >= 0; --e) {
    acc += __uint_as_float(buf[PIDX(tid * PPT + e)]);
    slog += __logf(acc + O);
  }
  for (int off = 32; off; off >>= 1) slog += __shfl_down(slog, off);
  if (lane == 0) wmax[wave] = slog;
  __syncthreads();
  if (tid == 0) {
    float t = wmax[0] + wmax[1] + wmax[2] + wmax[3];
    float rowval = (float)L * M + t - S;
    atomicAdd(out, rowval * invB);
  }
}

extern "C" void kernel_launch(void* const* d_in, const int* in_sizes, int n_in,
                              void* d_out, int out_size, void* d_ws, size_t ws_size,
                              hipStream_t stream) {
  const float* preds = (const float*)d_in[0];
  const float* labels = (const float*)d_in[1];
  float* out = (float*)d_out;
  const int B = in_sizes[0] / L;

  zero_out_kernel<<<1, 1, 0, stream>>>(out);
  listmle_kernel<<<B, NT, 0, stream>>>(preds, labels, out, 1.0f / (float)B);
}